// Round 11
// baseline (497.410 us; speedup 1.0000x reference)
//
#include <hip/hip_runtime.h>

#define B_ 32
#define DIM_ 512
#define N_ 2048
#define R_ 64
#define K_ 6
#define EPS_ 2e-8f

typedef short bf16x8 __attribute__((ext_vector_type(8)));
typedef float f32x4 __attribute__((ext_vector_type(4)));

__device__ __forceinline__ unsigned short f2bf(float f) {
  unsigned u = __float_as_uint(f);
  unsigned r = (u + 0x7FFFu + ((u >> 16) & 1u)) >> 16;  // RNE, finite nonneg inputs
  return (unsigned short)r;
}
__device__ __forceinline__ float bf2f(unsigned short h) {
  return __uint_as_float(((unsigned)h) << 16);
}

// ============ one-time: relu(x) -> xbf [b][d][n], xbt [b][n][d] (both bf16) ============
// grid (N/64, DIM/64, B), 256 thr
__global__ __launch_bounds__(256) void k_xprep(const float* __restrict__ x, short* __restrict__ xbf,
                                               short* __restrict__ xbt) {
  const int b = blockIdx.z, d0 = blockIdx.y * 64, n0 = blockIdx.x * 64;
  const int t = threadIdx.x;
  __shared__ float tile[64 * 65];  // bf16 value in high 16 bits; pitch 65
  const float* xg = x + (size_t)b * DIM_ * N_ + (size_t)d0 * N_ + n0;
  short* xn = xbf + (size_t)b * DIM_ * N_ + (size_t)d0 * N_ + n0;
#pragma unroll
  for (int i = 0; i < 2; ++i) {
    int idx = i * 256 + t;
    int d = idx >> 3, c = idx & 7;
    float4 a = *(const float4*)(xg + (size_t)d * N_ + c * 8);
    float4 e = *(const float4*)(xg + (size_t)d * N_ + c * 8 + 4);
    unsigned h[8];
    h[0] = f2bf(fmaxf(a.x, 0.f)); h[1] = f2bf(fmaxf(a.y, 0.f));
    h[2] = f2bf(fmaxf(a.z, 0.f)); h[3] = f2bf(fmaxf(a.w, 0.f));
    h[4] = f2bf(fmaxf(e.x, 0.f)); h[5] = f2bf(fmaxf(e.y, 0.f));
    h[6] = f2bf(fmaxf(e.z, 0.f)); h[7] = f2bf(fmaxf(e.w, 0.f));
    unsigned o[4];
#pragma unroll
    for (int k = 0; k < 4; ++k) o[k] = h[2 * k] | (h[2 * k + 1] << 16);
    *(int4*)(xn + (size_t)d * N_ + c * 8) = *(const int4*)o;
#pragma unroll
    for (int j = 0; j < 8; ++j) tile[d * 65 + c * 8 + j] = __uint_as_float(h[j] << 16);
  }
  __syncthreads();
  short* xt = xbt + (size_t)b * N_ * DIM_ + (size_t)n0 * DIM_ + d0;
#pragma unroll
  for (int i = 0; i < 2; ++i) {
    int idx = i * 256 + t;
    int n = idx >> 3, c = idx & 7;
    unsigned o[4];
#pragma unroll
    for (int k = 0; k < 4; ++k) {
      unsigned lo = __float_as_uint(tile[(c * 8 + 2 * k) * 65 + n]);
      unsigned hi = __float_as_uint(tile[(c * 8 + 2 * k + 1) * 65 + n]);
      o[k] = (lo >> 16) | (hi & 0xFFFF0000u);
    }
    *(int4*)(xt + (size_t)n * DIM_ + c * 8) = *(const int4*)o;
  }
}

// ============ bcastD: D -> Db0 f32, Dbf0 [d][r], Dbt0 [r][d], DtD_part f32 [b][8] ============
// grid (8, B), 256 thr
__global__ __launch_bounds__(256) void k_bcastD(const float* __restrict__ D, float* __restrict__ Db,
                                                short* __restrict__ Dbf, short* __restrict__ Dbt,
                                                float* __restrict__ DtDp) {
  const int b = blockIdx.y, d0 = blockIdx.x * 64, t = threadIdx.x;
  const int w = t >> 6, ln = t & 15, lg = (t & 63) >> 4;
  __shared__ short dtt[64 * 72];  // [r][dl]
#pragma unroll
  for (int j = 0; j < 16; ++j) {
    int idx = t + j * 256;
    int d = idx >> 6, r = idx & 63;
    float v = D[(size_t)(d0 + d) * R_ + r];
    Db[((size_t)b * DIM_ + d0 + d) * R_ + r] = v;
    unsigned short h = f2bf(v);
    Dbf[((size_t)b * DIM_ + d0 + d) * R_ + r] = (short)h;
    dtt[r * 72 + d] = (short)h;
  }
  __syncthreads();
#pragma unroll
  for (int j = 0; j < 2; ++j) {
    int i = t + j * 256;
    int row = i >> 3, c = i & 7;
    *(int4*)(Dbt + ((size_t)b * R_ + row) * DIM_ + d0 + c * 8) = *(const int4*)(dtt + row * 72 + c * 8);
  }
  f32x4 g[4];
#pragma unroll
  for (int nt = 0; nt < 4; ++nt) g[nt] = (f32x4){0.f, 0.f, 0.f, 0.f};
#pragma unroll
  for (int kc = 0; kc < 2; ++kc) {
    bf16x8 a = *(const bf16x8*)(dtt + (w * 16 + ln) * 72 + kc * 32 + lg * 8);
#pragma unroll
    for (int nt = 0; nt < 4; ++nt) {
      bf16x8 bb = *(const bf16x8*)(dtt + (nt * 16 + ln) * 72 + kc * 32 + lg * 8);
      g[nt] = __builtin_amdgcn_mfma_f32_16x16x32_bf16(a, bb, g[nt], 0, 0, 0);
    }
  }
  float* Po = DtDp + ((size_t)b * 8 + blockIdx.x) * 4096;
#pragma unroll
  for (int nt = 0; nt < 4; ++nt)
#pragma unroll
    for (int q = 0; q < 4; ++q) Po[(w * 16 + lg * 4 + q) * 64 + nt * 16 + ln] = g[nt][q];
}

// ============ bcastC: C -> Cbf0 [r][n], Cbt0 [n][r], CCt_part f32 [b][16] ============
// grid (16, B), 256 thr
__global__ __launch_bounds__(256) void k_bcastC(const float* __restrict__ C,
                                                short* __restrict__ Cbf, short* __restrict__ Cbt,
                                                float* __restrict__ CCtp) {
  const int b = blockIdx.y, ns = blockIdx.x * 128, t = threadIdx.x;
  const int w = t >> 6, ln = t & 15, lg = (t & 63) >> 4;
  __shared__ short crt[64 * 136];  // [r][n]
  __shared__ short ctt[128 * 72];  // [n][r]
#pragma unroll
  for (int j = 0; j < 32; ++j) {
    int idx = t + j * 256;
    int r = idx >> 7, n = idx & 127;
    float v = C[(size_t)r * N_ + ns + n];
    unsigned short h = f2bf(v);
    Cbf[((size_t)b * R_ + r) * N_ + ns + n] = (short)h;
    crt[r * 136 + n] = (short)h;
    ctt[n * 72 + r] = (short)h;
  }
  __syncthreads();
#pragma unroll
  for (int j = 0; j < 4; ++j) {
    int i = t + j * 256;
    int row = i >> 3, c = i & 7;
    *(int4*)(Cbt + ((size_t)b * N_ + ns + row) * R_ + c * 8) = *(const int4*)(ctt + row * 72 + c * 8);
  }
  f32x4 g[4];
#pragma unroll
  for (int nt = 0; nt < 4; ++nt) g[nt] = (f32x4){0.f, 0.f, 0.f, 0.f};
#pragma unroll
  for (int kc = 0; kc < 4; ++kc) {
    bf16x8 a = *(const bf16x8*)(crt + (w * 16 + ln) * 136 + kc * 32 + lg * 8);
#pragma unroll
    for (int nt = 0; nt < 4; ++nt) {
      bf16x8 bb = *(const bf16x8*)(crt + (nt * 16 + ln) * 136 + kc * 32 + lg * 8);
      g[nt] = __builtin_amdgcn_mfma_f32_16x16x32_bf16(a, bb, g[nt], 0, 0, 0);
    }
  }
  float* Po = CCtp + ((size_t)b * 16 + blockIdx.x) * 4096;
#pragma unroll
  for (int nt = 0; nt < 4; ++nt)
#pragma unroll
    for (int q = 0; q < 4; ++q) Po[(w * 16 + lg * 4 + q) * 64 + nt * 16 + ln] = g[nt][q];
}

// ============ k_gram: reduce DtDp (8 slices) and CCtp (16 slices) -> bf16 finals [b][64][64] ============
// flat 256 blocks (8 per b), 256 thr. Per-element sum order identical to before -> bit-identical.
__global__ __launch_bounds__(256) void k_gram(const float* __restrict__ DtDp, const float* __restrict__ CCtp,
                                              short* __restrict__ dtdF, short* __restrict__ cctF) {
  const int b = blockIdx.x >> 3, g = blockIdx.x & 7;
  const int t = threadIdx.x;
  if (t < 128) {
    int idx4 = g * 128 + t;
    const float4* P = (const float4*)(DtDp + (size_t)b * 8 * 4096);
    float4 a = P[idx4];
#pragma unroll
    for (int ss = 1; ss < 8; ++ss) {
      float4 v = P[ss * 1024 + idx4];
      a.x += v.x; a.y += v.y; a.z += v.z; a.w += v.w;
    }
    unsigned o0 = (unsigned)f2bf(a.x) | ((unsigned)f2bf(a.y) << 16);
    unsigned o1 = (unsigned)f2bf(a.z) | ((unsigned)f2bf(a.w) << 16);
    *(uint2*)(dtdF + (size_t)b * 4096 + idx4 * 4) = make_uint2(o0, o1);
  } else {
    int idx4 = g * 128 + (t - 128);
    const float4* P = (const float4*)(CCtp + (size_t)b * 16 * 4096);
    float4 a = P[idx4];
#pragma unroll
    for (int ss = 1; ss < 16; ++ss) {
      float4 v = P[ss * 1024 + idx4];
      a.x += v.x; a.y += v.y; a.z += v.z; a.w += v.w;
    }
    unsigned o0 = (unsigned)f2bf(a.x) | ((unsigned)f2bf(a.y) << 16);
    unsigned o1 = (unsigned)f2bf(a.z) | ((unsigned)f2bf(a.w) << 16);
    *(uint2*)(cctF + (size_t)b * 4096 + idx4 * 4) = make_uint2(o0, o1);
  }
}

// ============ fused: A = Dt@x (K=512; x LDS-dbuf, D-frags direct from L2-hot panel), denom, C update, mirrors, CCt partial ============
// flat grid 512 blocks (b = id&31 -> XCD affinity), 256 thr, 3 blk/CU
template <bool LAST>
__global__ __launch_bounds__(256, 3) void k_AC(
    const short* __restrict__ xbt, const short* __restrict__ Dbt_o,
    const short* __restrict__ Cbt_o, const short* __restrict__ dtdF,
    short* __restrict__ Cbf_n, short* __restrict__ Cbt_n, float* __restrict__ CCtp_n) {
  const int f = blockIdx.x;
  const int b = f & 31, nt_i = f >> 5;
  const int ns = nt_i * 128;
  const int t = threadIdx.x;
  const int w = t >> 6, ln = t & 15, lg = (t & 63) >> 4;
  __shared__ __align__(16) char smem[45056];
  short* xs0 = (short*)smem;             // [128][72] 18432 B
  short* xs1 = (short*)(smem + 18432);
  // phase-2 overlays (start after final barrier)
  short* dtd = (short*)smem;             // [64][72]   9216
  short* crt = (short*)(smem + 9216);    // [64][136] 17408
  short* ctt = (short*)(smem + 26624);   // [128][72] 18432

  const short* xg = xbt + ((size_t)b * N_ + ns) * DIM_;
  const short* dg = Dbt_o + (size_t)b * R_ * DIM_;
  int4 xv[4];

#define LOADX(kc)                                                                       \
  {                                                                                     \
    _Pragma("unroll") for (int j = 0; j < 4; ++j) {                                     \
      int idx = j * 256 + t;                                                            \
      xv[j] = *(const int4*)(xg + (size_t)(idx >> 3) * DIM_ + (kc) * 64 + (idx & 7) * 8); \
    }                                                                                   \
  }
#define STOREX(xs)                                                      \
  {                                                                     \
    _Pragma("unroll") for (int j = 0; j < 4; ++j) {                     \
      int idx = j * 256 + t;                                            \
      *(int4*)((xs) + (idx >> 3) * 72 + (idx & 7) * 8) = xv[j];         \
    }                                                                   \
  }

  f32x4 acc[4][2];
#pragma unroll
  for (int mt = 0; mt < 4; ++mt)
#pragma unroll
    for (int nt = 0; nt < 2; ++nt) acc[mt][nt] = (f32x4){0.f, 0.f, 0.f, 0.f};

  LOADX(0);
  STOREX(xs0);
  __syncthreads();
  for (int kc = 0; kc < 8; ++kc) {
    if (kc < 7) LOADX(kc + 1);
    short* xs = (kc & 1) ? xs1 : xs0;
    bf16x8 af2[2][4];  // D-fragments straight from global (64KB panel, L2-hot, XCD-local)
#pragma unroll
    for (int kk = 0; kk < 2; ++kk)
#pragma unroll
      for (int mt = 0; mt < 4; ++mt)
        af2[kk][mt] = *(const bf16x8*)(dg + (size_t)(mt * 16 + ln) * DIM_ + kc * 64 + kk * 32 + lg * 8);
#pragma unroll
    for (int kk = 0; kk < 2; ++kk) {
      bf16x8 bfv[2];
#pragma unroll
      for (int nt = 0; nt < 2; ++nt)
        bfv[nt] = *(const bf16x8*)(xs + (w * 32 + nt * 16 + ln) * 72 + kk * 32 + lg * 8);
#pragma unroll
      for (int mt = 0; mt < 4; ++mt)
#pragma unroll
        for (int nt = 0; nt < 2; ++nt)
          acc[mt][nt] = __builtin_amdgcn_mfma_f32_16x16x32_bf16(af2[kk][mt], bfv[nt], acc[mt][nt], 0, 0, 0);
    }
    if (kc < 7) {
      short* xsn = (kc & 1) ? xs0 : xs1;
      STOREX(xsn);
    }
    __syncthreads();
  }
#undef LOADX
#undef STOREX

  {  // DtD final (bf16, pre-reduced by k_gram) -> LDS
    const short* G = dtdF + (size_t)b * 4096;
#pragma unroll
    for (int j = 0; j < 2; ++j) {
      int i = t + j * 256;  // int4 index 0..511
      *(int4*)(dtd + (i >> 3) * 72 + (i & 7) * 8) = *(const int4*)(G + i * 8);
    }
  }
  __syncthreads();
  // denom = DtD @ C_old (bf16 MFMA, K=64); B-frags straight from global Cbt_o
  f32x4 accd[4][2];
#pragma unroll
  for (int mt = 0; mt < 4; ++mt)
#pragma unroll
    for (int nt = 0; nt < 2; ++nt) accd[mt][nt] = (f32x4){0.f, 0.f, 0.f, 0.f};
#pragma unroll
  for (int kc2 = 0; kc2 < 2; ++kc2) {
    bf16x8 cb[2], am[4];
#pragma unroll
    for (int nt = 0; nt < 2; ++nt)
      cb[nt] = *(const bf16x8*)(Cbt_o + ((size_t)b * N_ + ns + w * 32 + nt * 16 + ln) * R_ + kc2 * 32 + lg * 8);
#pragma unroll
    for (int mt = 0; mt < 4; ++mt) am[mt] = *(const bf16x8*)(dtd + (mt * 16 + ln) * 72 + kc2 * 32 + lg * 8);
#pragma unroll
    for (int mt = 0; mt < 4; ++mt)
#pragma unroll
      for (int nt = 0; nt < 2; ++nt)
        accd[mt][nt] = __builtin_amdgcn_mfma_f32_16x16x32_bf16(am[mt], cb[nt], accd[mt][nt], 0, 0, 0);
  }
  // update: C_new = C_old(bf16, via Cbt) * acc/(accd+eps); LDS mirrors only
#pragma unroll
  for (int mt = 0; mt < 4; ++mt)
#pragma unroll
    for (int nt = 0; nt < 2; ++nt) {
      int n = w * 32 + nt * 16 + ln;
      ushort4 cv = *(const ushort4*)(Cbt_o + ((size_t)b * N_ + ns + n) * R_ + mt * 16 + lg * 4);
      unsigned short cvv[4] = {cv.x, cv.y, cv.z, cv.w};
#pragma unroll
      for (int q = 0; q < 4; ++q) {
        int r = mt * 16 + lg * 4 + q;
        float co = bf2f(cvv[q]);
        float cn = co * acc[mt][nt][q] / (accd[mt][nt][q] + EPS_);
        unsigned short h = f2bf(cn);
        crt[r * 136 + n] = (short)h;
        ctt[n * 72 + r] = (short)h;
      }
    }
  __syncthreads();
  if constexpr (!LAST) {
#pragma unroll
    for (int j = 0; j < 4; ++j) {  // Cbf [64][128]
      int i = t + j * 256;
      int row = i >> 4, c = i & 15;
      *(int4*)(Cbf_n + ((size_t)b * R_ + row) * N_ + ns + c * 8) = *(const int4*)(crt + row * 136 + c * 8);
    }
  }
#pragma unroll
  for (int j = 0; j < 4; ++j) {  // Cbt [128][64]
    int i = t + j * 256;
    int row = i >> 3, c = i & 7;
    *(int4*)(Cbt_n + ((size_t)b * N_ + ns + row) * R_ + c * 8) = *(const int4*)(ctt + row * 72 + c * 8);
  }
  if constexpr (!LAST) {
    // CCt partial gram of C_new (K = 128 local cols)
    f32x4 g[4];
#pragma unroll
    for (int nt = 0; nt < 4; ++nt) g[nt] = (f32x4){0.f, 0.f, 0.f, 0.f};
#pragma unroll
    for (int kc3 = 0; kc3 < 4; ++kc3) {
      bf16x8 a = *(const bf16x8*)(crt + (w * 16 + ln) * 136 + kc3 * 32 + lg * 8);
#pragma unroll
      for (int nt2 = 0; nt2 < 4; ++nt2) {
        bf16x8 bb = *(const bf16x8*)(crt + (nt2 * 16 + ln) * 136 + kc3 * 32 + lg * 8);
        g[nt2] = __builtin_amdgcn_mfma_f32_16x16x32_bf16(a, bb, g[nt2], 0, 0, 0);
      }
    }
    float* Po = CCtp_n + ((size_t)b * 16 + nt_i) * 4096;
#pragma unroll
    for (int nt2 = 0; nt2 < 4; ++nt2)
#pragma unroll
      for (int q = 0; q < 4; ++q) Po[(w * 16 + lg * 4 + q) * 64 + nt2 * 16 + ln] = g[nt2][q];
  }
}

// ============ fused: XC = x@Ct (K=2048 ksplit2; x LDS-dbuf, C-frags direct from L2-hot panel), denom, D update, mirrors, DtD partial ============
// flat grid 256 blocks (b = id&31 -> XCD affinity), 512 thr, 3 blk/CU
template <bool LAST>
__global__ __launch_bounds__(512, 6) void k_XD(
    const short* __restrict__ xbf, const short* __restrict__ Cbf_o, const float* __restrict__ Db_o,
    const short* __restrict__ Dbf_o, const short* __restrict__ cctF, float* __restrict__ Db_n,
    short* __restrict__ Dbf_n, short* __restrict__ Dbt_n, float* __restrict__ DtDp_n) {
  const int f = blockIdx.x;
  const int b = f & 31, dt_i = f >> 5;
  const int d0 = dt_i * 64;
  const int t = threadIdx.x;
  const int w = t >> 6, ln = t & 15, lg = (t & 63) >> 4;
  const int kh = w >> 2, wq = w & 3;
  __shared__ __align__(16) char smem[36864];
  // staging: 2 dbuf sets x 2 x-tiles x [64][72] shorts (9216 B each)
  // phase-2 overlays:
  float* red = (float*)smem;             // 4096 f32 = 16384 B
  short* cct = (short*)(smem + 16384);   // [64][72] 9216 B
  short* dtt = (short*)(smem + 25600);   // [64][72] 9216 B

  const int tile = t >> 8, tt = t & 255;  // 2 groups of 256 thr, one x K-half tile each
  const short* gsrc = xbf + ((size_t)b * DIM_ + d0) * N_;
  const int nbase = tile * 1024;
  int4 v[2];

#define LOADV(kc)                                                                               \
  {                                                                                             \
    _Pragma("unroll") for (int j = 0; j < 2; ++j) {                                             \
      int idx = j * 256 + tt;                                                                   \
      v[j] = *(const int4*)(gsrc + (size_t)(idx >> 3) * N_ + nbase + (kc) * 64 + (idx & 7) * 8); \
    }                                                                                           \
  }
#define STOREV(pb)                                                                  \
  {                                                                                 \
    short* dst = (short*)(smem + ((pb) * 2 + tile) * 9216);                         \
    _Pragma("unroll") for (int j = 0; j < 2; ++j) {                                 \
      int idx = j * 256 + tt;                                                       \
      *(int4*)(dst + (idx >> 3) * 72 + (idx & 7) * 8) = v[j];                       \
    }                                                                               \
  }

  const short* cg = Cbf_o + (size_t)b * R_ * N_;  // C panel (256KB, L2-hot, XCD-local)
  f32x4 acc[4];
#pragma unroll
  for (int nt = 0; nt < 4; ++nt) acc[nt] = (f32x4){0.f, 0.f, 0.f, 0.f};

  LOADV(0);
  STOREV(0);
  __syncthreads();
  for (int cc = 0; cc < 16; ++cc) {
    if (cc < 15) LOADV(cc + 1);
    const int p = cc & 1;
    short* sx = (short*)(smem + (p * 2 + kh) * 9216);
    bf16x8 bb2[2][4];
#pragma unroll
    for (int kk = 0; kk < 2; ++kk)
#pragma unroll
      for (int nt = 0; nt < 4; ++nt)
        bb2[kk][nt] = *(const bf16x8*)(cg + (size_t)(nt * 16 + ln) * N_ + kh * 1024 + cc * 64 + kk * 32 + lg * 8);
#pragma unroll
    for (int kk = 0; kk < 2; ++kk) {
      bf16x8 a = *(const bf16x8*)(sx + (wq * 16 + ln) * 72 + kk * 32 + lg * 8);
#pragma unroll
      for (int nt = 0; nt < 4; ++nt)
        acc[nt] = __builtin_amdgcn_mfma_f32_16x16x32_bf16(a, bb2[kk][nt], acc[nt], 0, 0, 0);
    }
    if (cc < 15) STOREV((cc + 1) & 1);
    __syncthreads();
  }
#undef LOADV
#undef STOREV

  if (kh == 1) {
#pragma unroll
    for (int nt = 0; nt < 4; ++nt)
#pragma unroll
      for (int q = 0; q < 4; ++q) red[(wq * 16 + nt * 4 + q) * 64 + (t & 63)] = acc[nt][q];
  }
  {  // CCt final (bf16, pre-reduced by k_gram) -> LDS (512 int4, one per thread)
    const short* G = cctF + (size_t)b * 4096;
    *(int4*)(cct + (t >> 3) * 72 + (t & 7) * 8) = *(const int4*)(G + t * 8);
  }
  __syncthreads();
  if (kh == 0) {
#pragma unroll
    for (int nt = 0; nt < 4; ++nt)
#pragma unroll
      for (int q = 0; q < 4; ++q) acc[nt][q] += red[(wq * 16 + nt * 4 + q) * 64 + (t & 63)];
    f32x4 accd[4];
#pragma unroll
    for (int nt = 0; nt < 4; ++nt) accd[nt] = (f32x4){0.f, 0.f, 0.f, 0.f};
#pragma unroll
    for (int kc = 0; kc < 2; ++kc) {
      bf16x8 a = *(const bf16x8*)(Dbf_o + ((size_t)b * DIM_ + d0 + wq * 16 + ln) * R_ + kc * 32 + lg * 8);
#pragma unroll
      for (int nt = 0; nt < 4; ++nt) {
        bf16x8 bb = *(const bf16x8*)(cct + (nt * 16 + ln) * 72 + kc * 32 + lg * 8);
        accd[nt] = __builtin_amdgcn_mfma_f32_16x16x32_bf16(a, bb, accd[nt], 0, 0, 0);
      }
    }
#pragma unroll
    for (int nt = 0; nt < 4; ++nt)
#pragma unroll
      for (int q = 0; q < 4; ++q) {
        int dl = wq * 16 + lg * 4 + q;
        int r = nt * 16 + ln;
        size_t gi = ((size_t)b * DIM_ + d0 + dl) * R_ + r;
        float dold = Db_o[gi];
        float dn = dold * acc[nt][q] / (accd[nt][q] + EPS_);
        unsigned short h = f2bf(dn);
        Dbf_n[gi] = (short)h;
        if constexpr (!LAST) {
          Db_n[gi] = dn;
          dtt[r * 72 + dl] = (short)h;
        }
      }
  }
  __syncthreads();
  if constexpr (!LAST) {
    {  // Dbt write-out [64 r][64 d]
      int row = t >> 3, c = t & 7;
      *(int4*)(Dbt_n + ((size_t)b * R_ + row) * DIM_ + d0 + c * 8) = *(const int4*)(dtt + row * 72 + c * 8);
    }
    if (kh == 0) {  // DtD partial gram (K = 64 local d) -> f32 slice
      f32x4 g[4];
#pragma unroll
      for (int nt = 0; nt < 4; ++nt) g[nt] = (f32x4){0.f, 0.f, 0.f, 0.f};
#pragma unroll
      for (int kc = 0; kc < 2; ++kc) {
        bf16x8 a = *(const bf16x8*)(dtt + (wq * 16 + ln) * 72 + kc * 32 + lg * 8);
#pragma unroll
        for (int nt2 = 0; nt2 < 4; ++nt2) {
          bf16x8 bb = *(const bf16x8*)(dtt + (nt2 * 16 + ln) * 72 + kc * 32 + lg * 8);
          g[nt2] = __builtin_amdgcn_mfma_f32_16x16x32_bf16(a, bb, g[nt2], 0, 0, 0);
        }
      }
      float* Po = DtDp_n + ((size_t)b * 8 + dt_i) * 4096;
#pragma unroll
      for (int nt2 = 0; nt2 < 4; ++nt2)
#pragma unroll
        for (int q = 0; q < 4; ++q) Po[(wq * 16 + lg * 4 + q) * 64 + nt2 * 16 + ln] = g[nt2][q];
    }
  }
}

// ============ out[b,d,n] = sum_r Dbf[d,r] * Cbt[n,r]  (MFMA, K=64) ============
// grid (N/128, DIM/64, B), 256 thr
__global__ __launch_bounds__(256) void k_out(const short* __restrict__ Dbf, const short* __restrict__ Cbt,
                                             float* __restrict__ out) {
  const int b = blockIdx.z, d0 = blockIdx.y * 64, n0 = blockIdx.x * 128;
  const int t = threadIdx.x;
  const int w = t >> 6, ln = t & 15, lg = (t & 63) >> 4;
  __shared__ short ct[128 * 72];  // [n][r]
  __shared__ short dn[64 * 72];   // [d][r]
#pragma unroll
  for (int i = 0; i < 4; ++i) {
    int idx = i * 256 + t;
    int row = idx >> 3, c = idx & 7;
    *(int4*)(ct + row * 72 + c * 8) =
        *(const int4*)(Cbt + (size_t)b * N_ * R_ + (size_t)(n0 + row) * R_ + c * 8);
  }
#pragma unroll
  for (int i = 0; i < 2; ++i) {
    int idx = i * 256 + t;
    int row = idx >> 3, c = idx & 7;
    *(int4*)(dn + row * 72 + c * 8) =
        *(const int4*)(Dbf + (size_t)b * DIM_ * R_ + (size_t)(d0 + row) * R_ + c * 8);
  }
  __syncthreads();
  f32x4 acc[4][2];
#pragma unroll
  for (int mt = 0; mt < 4; ++mt)
#pragma unroll
    for (int nt = 0; nt < 2; ++nt) acc[mt][nt] = (f32x4){0.f, 0.f, 0.f, 0.f};
#pragma unroll
  for (int kc = 0; kc < 2; ++kc) {
    bf16x8 a[4], bb[2];
#pragma unroll
    for (int mt = 0; mt < 4; ++mt) a[mt] = *(const bf16x8*)(dn + (mt * 16 + ln) * 72 + kc * 32 + lg * 8);
#pragma unroll
    for (int nt = 0; nt < 2; ++nt)
      bb[nt] = *(const bf16x8*)(ct + (w * 32 + nt * 16 + ln) * 72 + kc * 32 + lg * 8);
#pragma unroll
    for (int mt = 0; mt < 4; ++mt)
#pragma unroll
      for (int nt = 0; nt < 2; ++nt)
        acc[mt][nt] = __builtin_amdgcn_mfma_f32_16x16x32_bf16(a[mt], bb[nt], acc[mt][nt], 0, 0, 0);
  }
  float* op = out + (size_t)b * DIM_ * N_;
#pragma unroll
  for (int mt = 0; mt < 4; ++mt)
#pragma unroll
    for (int nt = 0; nt < 2; ++nt) {
      int n = n0 + w * 32 + nt * 16 + ln;
#pragma unroll
      for (int q = 0; q < 4; ++q)
        op[(size_t)(d0 + mt * 16 + lg * 4 + q) * N_ + n] = acc[mt][nt][q];
    }
}

extern "C" void kernel_launch(void* const* d_in, const int* in_sizes, int n_in,
                              void* d_out, int out_size, void* d_ws, size_t ws_size,
                              hipStream_t stream) {
  const float* x = (const float*)d_in[0];
  const float* D = (const float*)d_in[1];
  const float* C = (const float*)d_in[2];
  float* out = (float*)d_out;

  // ---- ws (~96.6 MB) ----
  char* wsb = (char*)d_ws;
  short* xbf   = (short*)(wsb);                // 67,108,864  relu(x) bf16 [b][d][n]
  short* Cbf0  = (short*)(wsb + 67108864);     //  8,388,608  C state (bf16) [b][r][n]
  short* Cbt0  = (short*)(wsb + 75497472);     //  8,388,608  C^T mirror [b][n][r]
  float* Db0   = (float*)(wsb + 83886080);     //  4,194,304  D state f32
  short* Dbf0  = (short*)(wsb + 88080384);     //  2,097,152
  short* Dbt0  = (short*)(wsb + 90177536);     //  2,097,152
  float* DtDp0 = (float*)(wsb + 92274688);     //  4,194,304  f32 [b][8][64][64]
  float* DtDp1 = (float*)(wsb + 96468992);     //  4,194,304
  short* dtdF  = (short*)(wsb + 100663296);    //    262,144  bf16 [b][64][64]
  short* cctF  = (short*)(wsb + 100925440);    //    262,144  (ends 101,187,584)
  // ---- d_out overlay (k_out overwrites everything at the end) ----
  char* ob = (char*)d_out;
  short* xbt   = (short*)(ob);                 // 67,108,864  relu(x)^T bf16 [b][n][d]
  short* Cbf1  = (short*)(ob + 67108864);      //  8,388,608
  short* Cbt1  = (short*)(ob + 75497472);      //  8,388,608
  float* Db1   = (float*)(ob + 83886080);      //  4,194,304
  short* Dbf1  = (short*)(ob + 88080384);      //  2,097,152
  short* Dbt1  = (short*)(ob + 90177536);      //  2,097,152
  float* CCtp0 = (float*)(ob + 92274688);      //  8,388,608  f32 [b][16][64][64]
  float* CCtp1 = (float*)(ob + 100663296);     //  8,388,608  (ends 109,051,904 < 134,217,728)

  short* CbfS[2]  = {Cbf0, Cbf1};
  short* CbtS[2]  = {Cbt0, Cbt1};
  float* DbS[2]   = {Db0, Db1};
  short* DbfS[2]  = {Dbf0, Dbf1};
  short* DbtS[2]  = {Dbt0, Dbt1};
  float* DtDpS[2] = {DtDp0, DtDp1};
  float* CCtpS[2] = {CCtp0, CCtp1};

  k_xprep<<<dim3(N_ / 64, DIM_ / 64, B_), 256, 0, stream>>>(x, xbf, xbt);
  k_bcastD<<<dim3(8, B_), 256, 0, stream>>>(D, Db0, Dbf0, Dbt0, DtDp0);
  k_bcastC<<<dim3(16, B_), 256, 0, stream>>>(C, Cbf0, Cbt0, CCtp0);

  for (int k = 0; k < K_ - 1; ++k) {
    int p = k & 1, q = 1 - p;
    k_gram<<<dim3(256), 256, 0, stream>>>(DtDpS[p], CCtpS[p], dtdF, cctF);
    k_AC<false><<<dim3(512), 256, 0, stream>>>(xbt, DbtS[p], CbtS[p], dtdF,
                                               CbfS[q], CbtS[q], CCtpS[q]);
    k_XD<false><<<dim3(256), 512, 0, stream>>>(xbf, CbfS[p], DbS[p], DbfS[p], cctF,
                                               DbS[q], DbfS[q], DbtS[q], DtDpS[q]);
  }
  {  // k = 5 (LAST): p=1, q=0 -> final state lands in set 0 (ws); dead outputs skipped
    k_gram<<<dim3(256), 256, 0, stream>>>(DtDpS[1], CCtpS[1], dtdF, cctF);
    k_AC<true><<<dim3(512), 256, 0, stream>>>(xbt, DbtS[1], CbtS[1], dtdF,
                                              CbfS[0], CbtS[0], CCtpS[0]);
    k_XD<true><<<dim3(256), 512, 0, stream>>>(xbf, CbfS[1], DbS[1], DbfS[1], cctF,
                                              DbS[0], DbfS[0], DbtS[0], DtDpS[0]);
  }
  k_out<<<dim3(N_ / 128, DIM_ / 64, B_), 256, 0, stream>>>(Dbf0, Cbt0, out);
}

// Round 12
// 332.314 us; speedup vs baseline: 1.4968x; 1.4968x over previous
//
#include <hip/hip_runtime.h>

#define B_ 32
#define DIM_ 512
#define N_ 2048
#define R_ 64
#define K_ 6
#define EPS_ 2e-8f

typedef short bf16x8 __attribute__((ext_vector_type(8)));
typedef float f32x4 __attribute__((ext_vector_type(4)));

__device__ __forceinline__ unsigned short f2bf(float f) {
  unsigned u = __float_as_uint(f);
  unsigned r = (u + 0x7FFFu + ((u >> 16) & 1u)) >> 16;  // RNE, finite nonneg inputs
  return (unsigned short)r;
}
__device__ __forceinline__ float bf2f(unsigned short h) {
  return __uint_as_float(((unsigned)h) << 16);
}

// ============ one-time: relu(x) -> xbf [b][d][n], xbt [b][n][d] (both bf16) ============
// grid (N/64, DIM/64, B), 256 thr
__global__ __launch_bounds__(256) void k_xprep(const float* __restrict__ x, short* __restrict__ xbf,
                                               short* __restrict__ xbt) {
  const int b = blockIdx.z, d0 = blockIdx.y * 64, n0 = blockIdx.x * 64;
  const int t = threadIdx.x;
  __shared__ float tile[64 * 65];  // bf16 value in high 16 bits; pitch 65
  const float* xg = x + (size_t)b * DIM_ * N_ + (size_t)d0 * N_ + n0;
  short* xn = xbf + (size_t)b * DIM_ * N_ + (size_t)d0 * N_ + n0;
#pragma unroll
  for (int i = 0; i < 2; ++i) {
    int idx = i * 256 + t;
    int d = idx >> 3, c = idx & 7;
    float4 a = *(const float4*)(xg + (size_t)d * N_ + c * 8);
    float4 e = *(const float4*)(xg + (size_t)d * N_ + c * 8 + 4);
    unsigned h[8];
    h[0] = f2bf(fmaxf(a.x, 0.f)); h[1] = f2bf(fmaxf(a.y, 0.f));
    h[2] = f2bf(fmaxf(a.z, 0.f)); h[3] = f2bf(fmaxf(a.w, 0.f));
    h[4] = f2bf(fmaxf(e.x, 0.f)); h[5] = f2bf(fmaxf(e.y, 0.f));
    h[6] = f2bf(fmaxf(e.z, 0.f)); h[7] = f2bf(fmaxf(e.w, 0.f));
    unsigned o[4];
#pragma unroll
    for (int k = 0; k < 4; ++k) o[k] = h[2 * k] | (h[2 * k + 1] << 16);
    *(int4*)(xn + (size_t)d * N_ + c * 8) = *(const int4*)o;
#pragma unroll
    for (int j = 0; j < 8; ++j) tile[d * 65 + c * 8 + j] = __uint_as_float(h[j] << 16);
  }
  __syncthreads();
  short* xt = xbt + (size_t)b * N_ * DIM_ + (size_t)n0 * DIM_ + d0;
#pragma unroll
  for (int i = 0; i < 2; ++i) {
    int idx = i * 256 + t;
    int n = idx >> 3, c = idx & 7;
    unsigned o[4];
#pragma unroll
    for (int k = 0; k < 4; ++k) {
      unsigned lo = __float_as_uint(tile[(c * 8 + 2 * k) * 65 + n]);
      unsigned hi = __float_as_uint(tile[(c * 8 + 2 * k + 1) * 65 + n]);
      o[k] = (lo >> 16) | (hi & 0xFFFF0000u);
    }
    *(int4*)(xt + (size_t)n * DIM_ + c * 8) = *(const int4*)o;
  }
}

// ============ bcastD: D -> Db0 f32, Dbf0 [d][r], Dbt0 [r][d], DtD_part f32 [b][8] ============
// grid (8, B), 256 thr
__global__ __launch_bounds__(256) void k_bcastD(const float* __restrict__ D, float* __restrict__ Db,
                                                short* __restrict__ Dbf, short* __restrict__ Dbt,
                                                float* __restrict__ DtDp) {
  const int b = blockIdx.y, d0 = blockIdx.x * 64, t = threadIdx.x;
  const int w = t >> 6, ln = t & 15, lg = (t & 63) >> 4;
  __shared__ short dtt[64 * 72];  // [r][dl]
#pragma unroll
  for (int j = 0; j < 16; ++j) {
    int idx = t + j * 256;
    int d = idx >> 6, r = idx & 63;
    float v = D[(size_t)(d0 + d) * R_ + r];
    Db[((size_t)b * DIM_ + d0 + d) * R_ + r] = v;
    unsigned short h = f2bf(v);
    Dbf[((size_t)b * DIM_ + d0 + d) * R_ + r] = (short)h;
    dtt[r * 72 + d] = (short)h;
  }
  __syncthreads();
#pragma unroll
  for (int j = 0; j < 2; ++j) {
    int i = t + j * 256;
    int row = i >> 3, c = i & 7;
    *(int4*)(Dbt + ((size_t)b * R_ + row) * DIM_ + d0 + c * 8) = *(const int4*)(dtt + row * 72 + c * 8);
  }
  f32x4 g[4];
#pragma unroll
  for (int nt = 0; nt < 4; ++nt) g[nt] = (f32x4){0.f, 0.f, 0.f, 0.f};
#pragma unroll
  for (int kc = 0; kc < 2; ++kc) {
    bf16x8 a = *(const bf16x8*)(dtt + (w * 16 + ln) * 72 + kc * 32 + lg * 8);
#pragma unroll
    for (int nt = 0; nt < 4; ++nt) {
      bf16x8 bb = *(const bf16x8*)(dtt + (nt * 16 + ln) * 72 + kc * 32 + lg * 8);
      g[nt] = __builtin_amdgcn_mfma_f32_16x16x32_bf16(a, bb, g[nt], 0, 0, 0);
    }
  }
  float* Po = DtDp + ((size_t)b * 8 + blockIdx.x) * 4096;
#pragma unroll
  for (int nt = 0; nt < 4; ++nt)
#pragma unroll
    for (int q = 0; q < 4; ++q) Po[(w * 16 + lg * 4 + q) * 64 + nt * 16 + ln] = g[nt][q];
}

// ============ bcastC: C -> Cbf0 [r][n], Cbt0 [n][r], CCt_part f32 [b][16] ============
// grid (16, B), 256 thr
__global__ __launch_bounds__(256) void k_bcastC(const float* __restrict__ C,
                                                short* __restrict__ Cbf, short* __restrict__ Cbt,
                                                float* __restrict__ CCtp) {
  const int b = blockIdx.y, ns = blockIdx.x * 128, t = threadIdx.x;
  const int w = t >> 6, ln = t & 15, lg = (t & 63) >> 4;
  __shared__ short crt[64 * 136];  // [r][n]
  __shared__ short ctt[128 * 72];  // [n][r]
#pragma unroll
  for (int j = 0; j < 32; ++j) {
    int idx = t + j * 256;
    int r = idx >> 7, n = idx & 127;
    float v = C[(size_t)r * N_ + ns + n];
    unsigned short h = f2bf(v);
    Cbf[((size_t)b * R_ + r) * N_ + ns + n] = (short)h;
    crt[r * 136 + n] = (short)h;
    ctt[n * 72 + r] = (short)h;
  }
  __syncthreads();
#pragma unroll
  for (int j = 0; j < 4; ++j) {
    int i = t + j * 256;
    int row = i >> 3, c = i & 7;
    *(int4*)(Cbt + ((size_t)b * N_ + ns + row) * R_ + c * 8) = *(const int4*)(ctt + row * 72 + c * 8);
  }
  f32x4 g[4];
#pragma unroll
  for (int nt = 0; nt < 4; ++nt) g[nt] = (f32x4){0.f, 0.f, 0.f, 0.f};
#pragma unroll
  for (int kc = 0; kc < 4; ++kc) {
    bf16x8 a = *(const bf16x8*)(crt + (w * 16 + ln) * 136 + kc * 32 + lg * 8);
#pragma unroll
    for (int nt = 0; nt < 4; ++nt) {
      bf16x8 bb = *(const bf16x8*)(crt + (nt * 16 + ln) * 136 + kc * 32 + lg * 8);
      g[nt] = __builtin_amdgcn_mfma_f32_16x16x32_bf16(a, bb, g[nt], 0, 0, 0);
    }
  }
  float* Po = CCtp + ((size_t)b * 16 + blockIdx.x) * 4096;
#pragma unroll
  for (int nt = 0; nt < 4; ++nt)
#pragma unroll
    for (int q = 0; q < 4; ++q) Po[(w * 16 + lg * 4 + q) * 64 + nt * 16 + ln] = g[nt][q];
}

// ============ k_gram: reduce DtDp (8 slices) and CCtp (16 slices) -> bf16 finals [b][64][64] ============
// flat 256 blocks (8 per b), 256 thr. Per-element sum order identical -> bit-identical results.
__global__ __launch_bounds__(256) void k_gram(const float* __restrict__ DtDp, const float* __restrict__ CCtp,
                                              short* __restrict__ dtdF, short* __restrict__ cctF) {
  const int b = blockIdx.x >> 3, g = blockIdx.x & 7;
  const int t = threadIdx.x;
  if (t < 128) {
    int idx4 = g * 128 + t;
    const float4* P = (const float4*)(DtDp + (size_t)b * 8 * 4096);
    float4 a = P[idx4];
#pragma unroll
    for (int ss = 1; ss < 8; ++ss) {
      float4 v = P[ss * 1024 + idx4];
      a.x += v.x; a.y += v.y; a.z += v.z; a.w += v.w;
    }
    unsigned o0 = (unsigned)f2bf(a.x) | ((unsigned)f2bf(a.y) << 16);
    unsigned o1 = (unsigned)f2bf(a.z) | ((unsigned)f2bf(a.w) << 16);
    *(uint2*)(dtdF + (size_t)b * 4096 + idx4 * 4) = make_uint2(o0, o1);
  } else {
    int idx4 = g * 128 + (t - 128);
    const float4* P = (const float4*)(CCtp + (size_t)b * 16 * 4096);
    float4 a = P[idx4];
#pragma unroll
    for (int ss = 1; ss < 16; ++ss) {
      float4 v = P[ss * 1024 + idx4];
      a.x += v.x; a.y += v.y; a.z += v.z; a.w += v.w;
    }
    unsigned o0 = (unsigned)f2bf(a.x) | ((unsigned)f2bf(a.y) << 16);
    unsigned o1 = (unsigned)f2bf(a.z) | ((unsigned)f2bf(a.w) << 16);
    *(uint2*)(cctF + (size_t)b * 4096 + idx4 * 4) = make_uint2(o0, o1);
  }
}

// ============ fused: A = Dt@x (K=512, dbuf K-chunk 64, x+D LDS-staged), denom = DtD@C, C update, mirrors, CCt partial ============
// flat grid 512 blocks (b = id&31 -> XCD affinity), 256 thr
template <bool LAST>
__global__ __launch_bounds__(256, 2) void k_AC(
    const short* __restrict__ xbt, const short* __restrict__ Dbt_o,
    const short* __restrict__ Cbt_o, const short* __restrict__ dtdF,
    short* __restrict__ Cbf_n, short* __restrict__ Cbt_n, float* __restrict__ CCtp_n) {
  const int f = blockIdx.x;
  const int b = f & 31, nt_i = f >> 5;
  const int ns = nt_i * 128;
  const int t = threadIdx.x;
  const int w = t >> 6, ln = t & 15, lg = (t & 63) >> 4;
  __shared__ __align__(16) char smem[55296];
  short* xs0 = (short*)smem;             // [128][72] 18432 B
  short* xs1 = (short*)(smem + 18432);
  short* ds0 = (short*)(smem + 36864);   // [64][72] 9216 B
  short* ds1 = (short*)(smem + 46080);
  // phase-2 overlays (start after final barrier)
  short* dtd = (short*)smem;             // [64][72]   9216
  short* crt = (short*)(smem + 9216);    // [64][136] 17408
  short* ctt = (short*)(smem + 26624);   // [128][72] 18432

  const short* xg = xbt + ((size_t)b * N_ + ns) * DIM_;
  const short* dg = Dbt_o + (size_t)b * R_ * DIM_;
  int4 xv[4], dv[2];

#define LOADX(kc)                                                                       \
  {                                                                                     \
    _Pragma("unroll") for (int j = 0; j < 4; ++j) {                                     \
      int idx = j * 256 + t;                                                            \
      xv[j] = *(const int4*)(xg + (size_t)(idx >> 3) * DIM_ + (kc) * 64 + (idx & 7) * 8); \
    }                                                                                   \
    _Pragma("unroll") for (int j = 0; j < 2; ++j) {                                     \
      int idx = j * 256 + t;                                                            \
      dv[j] = *(const int4*)(dg + (size_t)(idx >> 3) * DIM_ + (kc) * 64 + (idx & 7) * 8); \
    }                                                                                   \
  }
#define STOREX(xs, ds)                                                  \
  {                                                                     \
    _Pragma("unroll") for (int j = 0; j < 4; ++j) {                     \
      int idx = j * 256 + t;                                            \
      *(int4*)((xs) + (idx >> 3) * 72 + (idx & 7) * 8) = xv[j];         \
    }                                                                   \
    _Pragma("unroll") for (int j = 0; j < 2; ++j) {                     \
      int idx = j * 256 + t;                                            \
      *(int4*)((ds) + (idx >> 3) * 72 + (idx & 7) * 8) = dv[j];         \
    }                                                                   \
  }

  f32x4 acc[4][2];
#pragma unroll
  for (int mt = 0; mt < 4; ++mt)
#pragma unroll
    for (int nt = 0; nt < 2; ++nt) acc[mt][nt] = (f32x4){0.f, 0.f, 0.f, 0.f};

  LOADX(0);
  STOREX(xs0, ds0);
  __syncthreads();
  for (int kc = 0; kc < 8; ++kc) {
    if (kc < 7) LOADX(kc + 1);
    short* xs = (kc & 1) ? xs1 : xs0;
    short* ds = (kc & 1) ? ds1 : ds0;
#pragma unroll
    for (int kk = 0; kk < 2; ++kk) {
      bf16x8 af[4], bfv[2];
#pragma unroll
      for (int mt = 0; mt < 4; ++mt) af[mt] = *(const bf16x8*)(ds + (mt * 16 + ln) * 72 + kk * 32 + lg * 8);
#pragma unroll
      for (int nt = 0; nt < 2; ++nt)
        bfv[nt] = *(const bf16x8*)(xs + (w * 32 + nt * 16 + ln) * 72 + kk * 32 + lg * 8);
#pragma unroll
      for (int mt = 0; mt < 4; ++mt)
#pragma unroll
        for (int nt = 0; nt < 2; ++nt)
          acc[mt][nt] = __builtin_amdgcn_mfma_f32_16x16x32_bf16(af[mt], bfv[nt], acc[mt][nt], 0, 0, 0);
    }
    if (kc < 7) {
      short* xsn = (kc & 1) ? xs0 : xs1;
      short* dsn = (kc & 1) ? ds0 : ds1;
      STOREX(xsn, dsn);
    }
    __syncthreads();
  }
#undef LOADX
#undef STOREX

  {  // DtD final (bf16, pre-reduced by k_gram) -> LDS
    const short* G = dtdF + (size_t)b * 4096;
#pragma unroll
    for (int j = 0; j < 2; ++j) {
      int i = t + j * 256;  // int4 index 0..511
      *(int4*)(dtd + (i >> 3) * 72 + (i & 7) * 8) = *(const int4*)(G + i * 8);
    }
  }
  __syncthreads();
  // denom = DtD @ C_old (bf16 MFMA, K=64); B-frags straight from global Cbt_o
  f32x4 accd[4][2];
#pragma unroll
  for (int mt = 0; mt < 4; ++mt)
#pragma unroll
    for (int nt = 0; nt < 2; ++nt) accd[mt][nt] = (f32x4){0.f, 0.f, 0.f, 0.f};
#pragma unroll
  for (int kc2 = 0; kc2 < 2; ++kc2) {
    bf16x8 cb[2], am[4];
#pragma unroll
    for (int nt = 0; nt < 2; ++nt)
      cb[nt] = *(const bf16x8*)(Cbt_o + ((size_t)b * N_ + ns + w * 32 + nt * 16 + ln) * R_ + kc2 * 32 + lg * 8);
#pragma unroll
    for (int mt = 0; mt < 4; ++mt) am[mt] = *(const bf16x8*)(dtd + (mt * 16 + ln) * 72 + kc2 * 32 + lg * 8);
#pragma unroll
    for (int mt = 0; mt < 4; ++mt)
#pragma unroll
      for (int nt = 0; nt < 2; ++nt)
        accd[mt][nt] = __builtin_amdgcn_mfma_f32_16x16x32_bf16(am[mt], cb[nt], accd[mt][nt], 0, 0, 0);
  }
  // update: C_new = C_old(bf16, via Cbt) * acc/(accd+eps); LDS mirrors only
#pragma unroll
  for (int mt = 0; mt < 4; ++mt)
#pragma unroll
    for (int nt = 0; nt < 2; ++nt) {
      int n = w * 32 + nt * 16 + ln;
      ushort4 cv = *(const ushort4*)(Cbt_o + ((size_t)b * N_ + ns + n) * R_ + mt * 16 + lg * 4);
      unsigned short cvv[4] = {cv.x, cv.y, cv.z, cv.w};
#pragma unroll
      for (int q = 0; q < 4; ++q) {
        int r = mt * 16 + lg * 4 + q;
        float co = bf2f(cvv[q]);
        float cn = co * acc[mt][nt][q] / (accd[mt][nt][q] + EPS_);
        unsigned short h = f2bf(cn);
        crt[r * 136 + n] = (short)h;
        ctt[n * 72 + r] = (short)h;
      }
    }
  __syncthreads();
  if constexpr (!LAST) {
#pragma unroll
    for (int j = 0; j < 4; ++j) {  // Cbf [64][128]
      int i = t + j * 256;
      int row = i >> 4, c = i & 15;
      *(int4*)(Cbf_n + ((size_t)b * R_ + row) * N_ + ns + c * 8) = *(const int4*)(crt + row * 136 + c * 8);
    }
  }
#pragma unroll
  for (int j = 0; j < 4; ++j) {  // Cbt [128][64]
    int i = t + j * 256;
    int row = i >> 3, c = i & 7;
    *(int4*)(Cbt_n + ((size_t)b * N_ + ns + row) * R_ + c * 8) = *(const int4*)(ctt + row * 72 + c * 8);
  }
  if constexpr (!LAST) {
    // CCt partial gram of C_new (K = 128 local cols)
    f32x4 g[4];
#pragma unroll
    for (int nt = 0; nt < 4; ++nt) g[nt] = (f32x4){0.f, 0.f, 0.f, 0.f};
#pragma unroll
    for (int kc3 = 0; kc3 < 4; ++kc3) {
      bf16x8 a = *(const bf16x8*)(crt + (w * 16 + ln) * 136 + kc3 * 32 + lg * 8);
#pragma unroll
      for (int nt2 = 0; nt2 < 4; ++nt2) {
        bf16x8 bb = *(const bf16x8*)(crt + (nt2 * 16 + ln) * 136 + kc3 * 32 + lg * 8);
        g[nt2] = __builtin_amdgcn_mfma_f32_16x16x32_bf16(a, bb, g[nt2], 0, 0, 0);
      }
    }
    float* Po = CCtp_n + ((size_t)b * 16 + nt_i) * 4096;
#pragma unroll
    for (int nt2 = 0; nt2 < 4; ++nt2)
#pragma unroll
      for (int q = 0; q < 4; ++q) Po[(w * 16 + lg * 4 + q) * 64 + nt2 * 16 + ln] = g[nt2][q];
  }
}

// ============ fused: XC = x@Ct (K=2048 ksplit2-in-block, dbuf K-chunk 64, x+C LDS-staged), denom, D update, mirrors, DtD partial ============
// flat grid 256 blocks (b = id&31 -> XCD affinity), 512 thr
template <bool LAST>
__global__ __launch_bounds__(512, 2) void k_XD(
    const short* __restrict__ xbf, const short* __restrict__ Cbf_o, const float* __restrict__ Db_o,
    const short* __restrict__ Dbf_o, const short* __restrict__ cctF, float* __restrict__ Db_n,
    short* __restrict__ Dbf_n, short* __restrict__ Dbt_n, float* __restrict__ DtDp_n) {
  const int f = blockIdx.x;
  const int b = f & 31, dt_i = f >> 5;
  const int d0 = dt_i * 64;
  const int t = threadIdx.x;
  const int w = t >> 6, ln = t & 15, lg = (t & 63) >> 4;
  const int kh = w >> 2, wq = w & 3;
  __shared__ __align__(16) char smem[73728];
  // staging: 2 dbuf sets x 4 tiles x [64][72] shorts (9216 B each)
  // phase-2 overlays:
  float* red = (float*)smem;             // 4096 f32 = 16384 B
  short* cct = (short*)(smem + 16384);   // [64][72] 9216 B
  short* dtt = (short*)(smem + 25600);   // [64][72] 9216 B

  const int tsel = t >> 7, tt = t & 127;
  const short* gsrc = (tsel & 1) ? (Cbf_o + (size_t)b * R_ * N_) : (xbf + ((size_t)b * DIM_ + d0) * N_);
  const int nbase = (tsel >> 1) * 1024;
  int4 v[4];

#define LOADV(kc)                                                                         \
  {                                                                                       \
    _Pragma("unroll") for (int j = 0; j < 4; ++j) {                                       \
      int idx = j * 128 + tt;                                                             \
      v[j] = *(const int4*)(gsrc + (size_t)(idx >> 3) * N_ + nbase + (kc) * 64 + (idx & 7) * 8); \
    }                                                                                     \
  }
#define STOREV(pb)                                                                  \
  {                                                                                 \
    short* dst = (short*)(smem + ((pb) * 4 + tsel) * 9216);                         \
    _Pragma("unroll") for (int j = 0; j < 4; ++j) {                                 \
      int idx = j * 128 + tt;                                                       \
      *(int4*)(dst + (idx >> 3) * 72 + (idx & 7) * 8) = v[j];                       \
    }                                                                               \
  }

  f32x4 acc[4];
#pragma unroll
  for (int nt = 0; nt < 4; ++nt) acc[nt] = (f32x4){0.f, 0.f, 0.f, 0.f};

  LOADV(0);
  STOREV(0);
  __syncthreads();
  for (int cc = 0; cc < 16; ++cc) {
    if (cc < 15) LOADV(cc + 1);
    const int p = cc & 1;
    short* sx = (short*)(smem + (p * 4 + kh * 2) * 9216);
    short* sc = (short*)(smem + (p * 4 + kh * 2 + 1) * 9216);
#pragma unroll
    for (int kk = 0; kk < 2; ++kk) {
      bf16x8 a = *(const bf16x8*)(sx + (wq * 16 + ln) * 72 + kk * 32 + lg * 8);
#pragma unroll
      for (int nt = 0; nt < 4; ++nt) {
        bf16x8 bb = *(const bf16x8*)(sc + (nt * 16 + ln) * 72 + kk * 32 + lg * 8);
        acc[nt] = __builtin_amdgcn_mfma_f32_16x16x32_bf16(a, bb, acc[nt], 0, 0, 0);
      }
    }
    if (cc < 15) STOREV((cc + 1) & 1);
    __syncthreads();
  }
#undef LOADV
#undef STOREV

  if (kh == 1) {
#pragma unroll
    for (int nt = 0; nt < 4; ++nt)
#pragma unroll
      for (int q = 0; q < 4; ++q) red[(wq * 16 + nt * 4 + q) * 64 + (t & 63)] = acc[nt][q];
  }
  {  // CCt final (bf16, pre-reduced by k_gram) -> LDS (512 int4, one per thread)
    const short* G = cctF + (size_t)b * 4096;
    *(int4*)(cct + (t >> 3) * 72 + (t & 7) * 8) = *(const int4*)(G + t * 8);
  }
  __syncthreads();
  if (kh == 0) {
#pragma unroll
    for (int nt = 0; nt < 4; ++nt)
#pragma unroll
      for (int q = 0; q < 4; ++q) acc[nt][q] += red[(wq * 16 + nt * 4 + q) * 64 + (t & 63)];
    f32x4 accd[4];
#pragma unroll
    for (int nt = 0; nt < 4; ++nt) accd[nt] = (f32x4){0.f, 0.f, 0.f, 0.f};
#pragma unroll
    for (int kc = 0; kc < 2; ++kc) {
      bf16x8 a = *(const bf16x8*)(Dbf_o + ((size_t)b * DIM_ + d0 + wq * 16 + ln) * R_ + kc * 32 + lg * 8);
#pragma unroll
      for (int nt = 0; nt < 4; ++nt) {
        bf16x8 bb = *(const bf16x8*)(cct + (nt * 16 + ln) * 72 + kc * 32 + lg * 8);
        accd[nt] = __builtin_amdgcn_mfma_f32_16x16x32_bf16(a, bb, accd[nt], 0, 0, 0);
      }
    }
#pragma unroll
    for (int nt = 0; nt < 4; ++nt)
#pragma unroll
      for (int q = 0; q < 4; ++q) {
        int dl = wq * 16 + lg * 4 + q;
        int r = nt * 16 + ln;
        size_t gi = ((size_t)b * DIM_ + d0 + dl) * R_ + r;
        float dold = Db_o[gi];
        float dn = dold * acc[nt][q] / (accd[nt][q] + EPS_);
        unsigned short h = f2bf(dn);
        Dbf_n[gi] = (short)h;
        if constexpr (!LAST) {
          Db_n[gi] = dn;
          dtt[r * 72 + dl] = (short)h;
        }
      }
  }
  __syncthreads();
  if constexpr (!LAST) {
    if (t < 512) {  // Dbt write-out [64 r][64 d]
      int row = t >> 3, c = t & 7;
      *(int4*)(Dbt_n + ((size_t)b * R_ + row) * DIM_ + d0 + c * 8) = *(const int4*)(dtt + row * 72 + c * 8);
    }
    if (kh == 0) {  // DtD partial gram (K = 64 local d) -> f32 slice
      f32x4 g[4];
#pragma unroll
      for (int nt = 0; nt < 4; ++nt) g[nt] = (f32x4){0.f, 0.f, 0.f, 0.f};
#pragma unroll
      for (int kc = 0; kc < 2; ++kc) {
        bf16x8 a = *(const bf16x8*)(dtt + (wq * 16 + ln) * 72 + kc * 32 + lg * 8);
#pragma unroll
        for (int nt2 = 0; nt2 < 4; ++nt2) {
          bf16x8 bb = *(const bf16x8*)(dtt + (nt2 * 16 + ln) * 72 + kc * 32 + lg * 8);
          g[nt2] = __builtin_amdgcn_mfma_f32_16x16x32_bf16(a, bb, g[nt2], 0, 0, 0);
        }
      }
      float* Po = DtDp_n + ((size_t)b * 8 + dt_i) * 4096;
#pragma unroll
      for (int nt2 = 0; nt2 < 4; ++nt2)
#pragma unroll
        for (int q = 0; q < 4; ++q) Po[(wq * 16 + lg * 4 + q) * 64 + nt2 * 16 + ln] = g[nt2][q];
    }
  }
}

// ============ out[b,d,n] = sum_r Dbf[d,r] * Cbt[n,r]  (MFMA, K=64) ============
// grid (N/128, DIM/64, B), 256 thr
__global__ __launch_bounds__(256) void k_out(const short* __restrict__ Dbf, const short* __restrict__ Cbt,
                                             float* __restrict__ out) {
  const int b = blockIdx.z, d0 = blockIdx.y * 64, n0 = blockIdx.x * 128;
  const int t = threadIdx.x;
  const int w = t >> 6, ln = t & 15, lg = (t & 63) >> 4;
  __shared__ short ct[128 * 72];  // [n][r]
  __shared__ short dn[64 * 72];   // [d][r]
#pragma unroll
  for (int i = 0; i < 4; ++i) {
    int idx = i * 256 + t;
    int row = idx >> 3, c = idx & 7;
    *(int4*)(ct + row * 72 + c * 8) =
        *(const int4*)(Cbt + (size_t)b * N_ * R_ + (size_t)(n0 + row) * R_ + c * 8);
  }
#pragma unroll
  for (int i = 0; i < 2; ++i) {
    int idx = i * 256 + t;
    int row = idx >> 3, c = idx & 7;
    *(int4*)(dn + row * 72 + c * 8) =
        *(const int4*)(Dbf + (size_t)b * DIM_ * R_ + (size_t)(d0 + row) * R_ + c * 8);
  }
  __syncthreads();
  f32x4 acc[4][2];
#pragma unroll
  for (int mt = 0; mt < 4; ++mt)
#pragma unroll
    for (int nt = 0; nt < 2; ++nt) acc[mt][nt] = (f32x4){0.f, 0.f, 0.f, 0.f};
#pragma unroll
  for (int kc = 0; kc < 2; ++kc) {
    bf16x8 a[4], bb[2];
#pragma unroll
    for (int mt = 0; mt < 4; ++mt) a[mt] = *(const bf16x8*)(dn + (mt * 16 + ln) * 72 + kc * 32 + lg * 8);
#pragma unroll
    for (int nt = 0; nt < 2; ++nt)
      bb[nt] = *(const bf16x8*)(ct + (w * 32 + nt * 16 + ln) * 72 + kc * 32 + lg * 8);
#pragma unroll
    for (int mt = 0; mt < 4; ++mt)
#pragma unroll
      for (int nt = 0; nt < 2; ++nt)
        acc[mt][nt] = __builtin_amdgcn_mfma_f32_16x16x32_bf16(a[mt], bb[nt], acc[mt][nt], 0, 0, 0);
  }
  float* op = out + (size_t)b * DIM_ * N_;
#pragma unroll
  for (int mt = 0; mt < 4; ++mt)
#pragma unroll
    for (int nt = 0; nt < 2; ++nt) {
      int n = n0 + w * 32 + nt * 16 + ln;
#pragma unroll
      for (int q = 0; q < 4; ++q)
        op[(size_t)(d0 + mt * 16 + lg * 4 + q) * N_ + n] = acc[mt][nt][q];
    }
}

extern "C" void kernel_launch(void* const* d_in, const int* in_sizes, int n_in,
                              void* d_out, int out_size, void* d_ws, size_t ws_size,
                              hipStream_t stream) {
  const float* x = (const float*)d_in[0];
  const float* D = (const float*)d_in[1];
  const float* C = (const float*)d_in[2];
  float* out = (float*)d_out;

  // ---- ws (~96.6 MB) ----
  char* wsb = (char*)d_ws;
  short* xbf   = (short*)(wsb);                // 67,108,864  relu(x) bf16 [b][d][n]
  short* Cbf0  = (short*)(wsb + 67108864);     //  8,388,608  C state (bf16) [b][r][n]
  short* Cbt0  = (short*)(wsb + 75497472);     //  8,388,608  C^T mirror [b][n][r]
  float* Db0   = (float*)(wsb + 83886080);     //  4,194,304  D state f32
  short* Dbf0  = (short*)(wsb + 88080384);     //  2,097,152
  short* Dbt0  = (short*)(wsb + 90177536);     //  2,097,152
  float* DtDp0 = (float*)(wsb + 92274688);     //  4,194,304  f32 [b][8][64][64]
  float* DtDp1 = (float*)(wsb + 96468992);     //  4,194,304
  short* dtdF  = (short*)(wsb + 100663296);    //    262,144  bf16 [b][64][64]
  short* cctF  = (short*)(wsb + 100925440);    //    262,144  (ends 101,187,584)
  // ---- d_out overlay (k_out overwrites everything at the end) ----
  char* ob = (char*)d_out;
  short* xbt   = (short*)(ob);                 // 67,108,864  relu(x)^T bf16 [b][n][d]
  short* Cbf1  = (short*)(ob + 67108864);      //  8,388,608
  short* Cbt1  = (short*)(ob + 75497472);      //  8,388,608
  float* Db1   = (float*)(ob + 83886080);      //  4,194,304
  short* Dbf1  = (short*)(ob + 88080384);      //  2,097,152
  short* Dbt1  = (short*)(ob + 90177536);      //  2,097,152
  float* CCtp0 = (float*)(ob + 92274688);      //  8,388,608  f32 [b][16][64][64]
  float* CCtp1 = (float*)(ob + 100663296);     //  8,388,608  (ends 109,051,904 < 134,217,728)

  short* CbfS[2]  = {Cbf0, Cbf1};
  short* CbtS[2]  = {Cbt0, Cbt1};
  float* DbS[2]   = {Db0, Db1};
  short* DbfS[2]  = {Dbf0, Dbf1};
  short* DbtS[2]  = {Dbt0, Dbt1};
  float* DtDpS[2] = {DtDp0, DtDp1};
  float* CCtpS[2] = {CCtp0, CCtp1};

  k_xprep<<<dim3(N_ / 64, DIM_ / 64, B_), 256, 0, stream>>>(x, xbf, xbt);
  k_bcastD<<<dim3(8, B_), 256, 0, stream>>>(D, Db0, Dbf0, Dbt0, DtDp0);
  k_bcastC<<<dim3(16, B_), 256, 0, stream>>>(C, Cbf0, Cbt0, CCtp0);

  for (int k = 0; k < K_ - 1; ++k) {
    int p = k & 1, q = 1 - p;
    k_gram<<<dim3(256), 256, 0, stream>>>(DtDpS[p], CCtpS[p], dtdF, cctF);
    k_AC<false><<<dim3(512), 256, 0, stream>>>(xbt, DbtS[p], CbtS[p], dtdF,
                                               CbfS[q], CbtS[q], CCtpS[q]);
    k_XD<false><<<dim3(256), 512, 0, stream>>>(xbf, CbfS[p], DbS[p], DbfS[p], cctF,
                                               DbS[q], DbfS[q], DbtS[q], DtDpS[q]);
  }
  {  // k = 5 (LAST): p=1, q=0 -> final state lands in set 0 (ws); dead outputs skipped
    k_gram<<<dim3(256), 256, 0, stream>>>(DtDpS[1], CCtpS[1], dtdF, cctF);
    k_AC<true><<<dim3(512), 256, 0, stream>>>(xbt, DbtS[1], CbtS[1], dtdF,
                                              CbfS[0], CbtS[0], CCtpS[0]);
    k_XD<true><<<dim3(256), 512, 0, stream>>>(xbf, CbfS[1], DbS[1], DbfS[1], cctF,
                                              DbS[0], DbfS[0], DbtS[0], DtDpS[0]);
  }
  k_out<<<dim3(N_ / 128, DIM_ / 64, B_), 256, 0, stream>>>(Dbf0, Cbt0, out);
}